// Round 7
// baseline (357.260 us; speedup 1.0000x reference)
//
#include <hip/hip_runtime.h>
#include <float.h>

#define NNODES 30000
#define NEDGES 480000
#define NFEATK 128
#define NH 16
#define NC 32
#define HC 512            // NH*NC
#define NCLASSES 10
#define NG 64
#define CAP 96            // padded per-node edge capacity (max deg ~45 for Poisson(16))

using half2v = __attribute__((ext_vector_type(2))) _Float16;
using half4 = __attribute__((ext_vector_type(4))) _Float16;
using half8 = __attribute__((ext_vector_type(8))) _Float16;
using f32x4 = __attribute__((ext_vector_type(4))) float;

// ---------------- prep: W transposes + bucket init (x-conversion folded into gemm1) ----------------
__global__ void prep0_kernel(const float* __restrict__ Wl1, const float* __restrict__ Wr1,
                             _Float16* __restrict__ Wlt1, _Float16* __restrict__ Wrt1,
                             const float* __restrict__ Wl2, const float* __restrict__ Wr2,
                             _Float16* __restrict__ Wlt2, _Float16* __restrict__ Wrt2,
                             int* __restrict__ cnt, unsigned short* __restrict__ csr) {
    int gtid = blockIdx.x * blockDim.x + threadIdx.x;
    int gstride = gridDim.x * blockDim.x;
    // W1 transposes (both l and r)
    for (int i = gtid; i < 2 * 512 * NFEATK; i += gstride) {
        int sel = i >= 512 * NFEATK;
        int idx = i - sel * 512 * NFEATK;
        const float* W = sel ? Wr1 : Wl1;
        _Float16* Wt = sel ? Wrt1 : Wlt1;
        int n = idx & 511, k = idx >> 9;
        Wt[n * NFEATK + k] = (_Float16)W[idx];
    }
    // W2 transposes
    for (int i = gtid; i < 2 * 512 * NC; i += gstride) {
        int sel = i >= 512 * NC;
        int idx = i - sel * 512 * NC;
        const float* W = sel ? Wr2 : Wl2;
        _Float16* Wt = sel ? Wrt2 : Wlt2;
        int n = idx & 511, k = idx >> 9;
        Wt[n * NC + k] = (_Float16)W[idx];
    }
    // bucket init: self-loop in slot 0, cnt = 1
    for (int i = gtid; i < NNODES; i += gstride) {
        cnt[i] = 1;
        csr[i * CAP] = (unsigned short)i;
    }
}

// ---------------- bucket scatter: one atomic pass, u16 payload ----------------
__global__ void scatter_kernel(const int* __restrict__ src, const int* __restrict__ dst,
                               int* __restrict__ cnt, unsigned short* __restrict__ csr) {
    int e = blockIdx.x * blockDim.x + threadIdx.x;
    if (e >= NEDGES) return;
    int s = src[e], d = dst[e];
    int pos = atomicAdd(&cnt[d], 1);
    csr[d * CAP + pos] = (unsigned short)s;
}

// ---------------- dual MFMA GEMM: merged-sel (one A-tile -> both Yl and Yr) ----------------
// K-split staging (KS=64). LDS: A 8KB + B 2x16KB = 40KB (K=128) / 20KB (K=32).
// A may be f32 (layer 1 reads x directly, converts in-register) or f16.
template <int K, typename AT>
__launch_bounds__(256)
__global__ void dual_gemm_kernel(const AT* __restrict__ A,
                                 const _Float16* __restrict__ Wlt, const _Float16* __restrict__ Wrt,
                                 const float* __restrict__ bl, const float* __restrict__ br,
                                 _Float16* __restrict__ Yl, _Float16* __restrict__ Yr) {
    constexpr int KS = (K > 64) ? 64 : K;    // staged K-chunk
    constexpr int KcS = KS / 8;              // half8 units per chunk row
    constexpr int AH = 64 * KS;
    constexpr int BH = 128 * KS;             // per sel
    constexpr int YSH = 64 * 136;
    constexpr int SMEMH = (AH + 2 * BH > YSH) ? (AH + 2 * BH) : YSH;
    __shared__ __align__(16) _Float16 smem[SMEMH];
    _Float16* as = smem;
    _Float16* bsl = smem + AH;
    _Float16* bsr = smem + AH + BH;

    int tid = threadIdx.x;
    int nbase = blockIdx.x * 128;            // 4 col-quadrants of 128
    int mb = blockIdx.y;

    int wave = tid >> 6, lane = tid & 63;
    int quad = lane >> 4, l16 = lane & 15;
    int am = l16 & (KcS - 1);

    f32x4 accl[8], accr[8];
    #pragma unroll
    for (int f = 0; f < 8; f++) {
        accl[f] = (f32x4){0.f, 0.f, 0.f, 0.f};
        accr[f] = (f32x4){0.f, 0.f, 0.f, 0.f};
    }

    #pragma unroll
    for (int ko = 0; ko < K / KS; ++ko) {
        if (ko) __syncthreads();             // protect LDS reuse across chunks
        for (int c = tid; c < 64 * KcS; c += 256) {
            int row = c / KcS, k8 = c % KcS;
            int arow = mb * 64 + row; if (arow > NNODES - 1) arow = NNODES - 1;
            half8 v;
            if constexpr (sizeof(AT) == 4) {
                const float* ap = (const float*)&A[(size_t)arow * K + (ko * KcS + k8) * 8];
                float4 f0 = *(const float4*)ap;
                float4 f1 = *(const float4*)(ap + 4);
                v = half8{(_Float16)f0.x, (_Float16)f0.y, (_Float16)f0.z, (_Float16)f0.w,
                          (_Float16)f1.x, (_Float16)f1.y, (_Float16)f1.z, (_Float16)f1.w};
            } else {
                v = *(const half8*)&A[(size_t)arow * K + (ko * KcS + k8) * 8];
            }
            *(half8*)&as[(row * KcS + (k8 ^ (row & (KcS - 1)))) * 8] = v;
        }
        for (int c = tid; c < 2 * 128 * KcS; c += 256) {
            int sel = c >= 128 * KcS;
            int cc = c - sel * 128 * KcS;
            int row = cc / KcS, k8 = cc % KcS;
            const _Float16* Bt = sel ? Wrt : Wlt;
            _Float16* bs = sel ? bsr : bsl;
            half8 v = *(const half8*)&Bt[(size_t)(nbase + row) * K + (ko * KcS + k8) * 8];
            *(half8*)&bs[(row * KcS + (k8 ^ (row & (KcS - 1)))) * 8] = v;
        }
        __syncthreads();

        #pragma unroll
        for (int kk = 0; kk < KcS; kk += 4) {
            int k8 = (kk + quad) ^ am;
            half8 a = *(const half8*)&as[((wave * 16 + l16) * KcS + k8) * 8];
            #pragma unroll
            for (int f = 0; f < 8; f++) {
                half8 b = *(const half8*)&bsl[((f * 16 + l16) * KcS + k8) * 8];
                accl[f] = __builtin_amdgcn_mfma_f32_16x16x32_f16(a, b, accl[f], 0, 0, 0);
            }
            #pragma unroll
            for (int f = 0; f < 8; f++) {
                half8 b = *(const half8*)&bsr[((f * 16 + l16) * KcS + k8) * 8];
                accr[f] = __builtin_amdgcn_mfma_f32_16x16x32_f16(a, b, accr[f], 0, 0, 0);
            }
        }
    }
    __syncthreads();

    _Float16* ys = smem;
    int mtop = mb * 64;
    // ---- Yl ----
    #pragma unroll
    for (int f = 0; f < 8; f++) {
        float bv = bl[nbase + f * 16 + l16];
        #pragma unroll
        for (int r = 0; r < 4; r++)
            ys[(wave * 16 + quad * 4 + r) * 136 + f * 16 + l16] = (_Float16)(accl[f][r] + bv);
    }
    __syncthreads();
    for (int c = tid; c < 64 * 16; c += 256) {
        int r = c >> 4, cc = (c & 15) * 8;
        int grow = mtop + r;
        if (grow < NNODES)
            *(half8*)&Yl[(size_t)grow * HC + nbase + cc] = *(half8*)&ys[r * 136 + cc];
    }
    __syncthreads();
    // ---- Yr ----
    #pragma unroll
    for (int f = 0; f < 8; f++) {
        float bv = br[nbase + f * 16 + l16];
        #pragma unroll
        for (int r = 0; r < 4; r++)
            ys[(wave * 16 + quad * 4 + r) * 136 + f * 16 + l16] = (_Float16)(accr[f][r] + bv);
    }
    __syncthreads();
    for (int c = tid; c < 64 * 16; c += 256) {
        int r = c >> 4, cc = (c & 15) * 8;
        int grow = mtop + r;
        if (grow < NNODES)
            *(half8*)&Yr[(size_t)grow * HC + nbase + cc] = *(half8*)&ys[r * 136 + cc];
    }
}

// ---------------- fused GATv2 edge stage: 4 nodes/block, 8-deep gather unroll ----------------
// 8 rows (8KB) in flight per wave to probe the per-CU miss-queue / in-flight-bytes limit.
__device__ inline half2v lrelu2(half2v e) {
    // leaky(e) = max(e, 0.2*e) since slope 0.2 in (0,1)
    half2v s = e * half2v{(_Float16)0.2f, (_Float16)0.2f};
    return __builtin_elementwise_max(e, s);
}

#if __has_builtin(__builtin_amdgcn_fdot2)
#define FDOT2(a, b, c) __builtin_amdgcn_fdot2((a), (b), (c), false)
#else
__device__ inline float fdot2_sw(half2v a, half2v b, float c) {
    half2v p = a * b;
    return c + (float)p.x + (float)p.y;
}
#define FDOT2(a, b, c) fdot2_sw((a), (b), (c))
#endif

template <typename OUT>
__launch_bounds__(256)
__global__ void gat_edge_kernel(const _Float16* __restrict__ xlh, const _Float16* __restrict__ xrh,
                                const float* __restrict__ att, const float* __restrict__ bvec,
                                const int* __restrict__ cnt, const unsigned short* __restrict__ csr_src,
                                OUT* __restrict__ hout) {
    int wv = threadIdx.x >> 6;           // wave in block -> node slot
    int t = threadIdx.x & 63;            // lane in wave
    int d = blockIdx.x * 4 + wv;         // dst node (NNODES % 4 == 0)
    int col = t * 8;                     // head = t/4, 4 lanes per head

    half8 xrq = *(const half8*)&xrh[(unsigned)d * HC + col];
    half2v xr0 = {xrq[0], xrq[1]}, xr1 = {xrq[2], xrq[3]};
    half2v xr2 = {xrq[4], xrq[5]}, xr3 = {xrq[6], xrq[7]};
    float4 atta = *(const float4*)&att[col];
    float4 attb = *(const float4*)&att[col + 4];
    half2v at0 = {(_Float16)atta.x, (_Float16)atta.y};
    half2v at1 = {(_Float16)atta.z, (_Float16)atta.w};
    half2v at2 = {(_Float16)attb.x, (_Float16)attb.y};
    half2v at3 = {(_Float16)attb.z, (_Float16)attb.w};

    int beg = d * CAP, end = beg + cnt[d];

    float l = 0.f;
    float a[8];
    #pragma unroll
    for (int c = 0; c < 8; c++) a[c] = 0.f;

    for (int i = beg; i < end; i += 8) {
        int n = end - i;                 // >= 1
        int sx[8];
        #pragma unroll
        for (int j = 0; j < 8; j++) sx[j] = csr_src[i + (j < n ? j : 0)];
        half8 q[8];
        #pragma unroll
        for (int j = 0; j < 8; j++) q[j] = *(const half8*)&xlh[(unsigned)sx[j] * HC + col];

        float v[8];
        #pragma unroll
        for (int j = 0; j < 8; j++) {
            float vv = 0.f;
            vv = FDOT2(lrelu2(half2v{q[j][0], q[j][1]} + xr0), at0, vv);
            vv = FDOT2(lrelu2(half2v{q[j][2], q[j][3]} + xr1), at1, vv);
            vv = FDOT2(lrelu2(half2v{q[j][4], q[j][5]} + xr2), at2, vv);
            vv = FDOT2(lrelu2(half2v{q[j][6], q[j][7]} + xr3), at3, vv);
            // head reduce: 4 lanes per head -> 2 butterfly levels
            vv += __shfl_xor(vv, 1);
            vv += __shfl_xor(vv, 2);
            v[j] = vv;
        }
        #pragma unroll
        for (int j = 0; j < 8; j++) {
            float p = (j < n) ? __expf(v[j]) : 0.f;
            l += p;
            #pragma unroll
            for (int c = 0; c < 8; c++) a[c] += p * (float)q[j][c];
        }
    }

    // normalize per (node, head) BEFORE head-mean: l is uniform within a
    // 4-lane head group, distinct across heads.
    float inv = 1.0f / l;
    #pragma unroll
    for (int c = 0; c < 8; c++) a[c] *= inv;

    // head-mean in-register: sum over the 16 lanes with equal (t & 3)
    #pragma unroll
    for (int off = 4; off < 64; off <<= 1) {
        #pragma unroll
        for (int c = 0; c < 8; c++) a[c] += __shfl_xor(a[c], off);
    }

    if (t < 4) {
        #pragma unroll
        for (int c = 0; c < 8; c++) {
            float r = a[c] * (1.0f / (float)NH) + bvec[t * 8 + c];
            r = (r > 0.f) ? r : 0.01f * r;
            hout[(size_t)d * NC + t * 8 + c] = (OUT)r;
        }
    }
}

// ---------------- fused pool + classifier (unchanged) ----------------
__launch_bounds__(1024)
__global__ void pool_classify_kernel(const float* __restrict__ h, const int* __restrict__ batch,
                                     const float* __restrict__ Wc, const float* __restrict__ bc,
                                     float* __restrict__ out) {
    int g = blockIdx.x;
    int lo = 0, hi = NNODES;
    while (lo < hi) { int mid = (lo + hi) >> 1; if (batch[mid] < g) lo = mid + 1; else hi = mid; }
    int start = lo;
    hi = NNODES;
    while (lo < hi) { int mid = (lo + hi) >> 1; if (batch[mid] <= g) lo = mid + 1; else hi = mid; }
    int endn = lo;
    int cntg = endn - start;

    int tid = threadIdx.x;
    int c = tid & 31, nl = tid >> 5;              // 32 node-lanes x 32 channels
    float s = 0.f;
    for (int n = start + nl; n < endn; n += 32) s += h[n * NC + c];
    __shared__ float red[1024];
    red[tid] = s;
    __syncthreads();
    if (tid < 32) {
        float t = 0.f;
        #pragma unroll
        for (int j = 0; j < 32; j++) t += red[j * 32 + tid];
        red[tid] = t / fmaxf((float)cntg, 1.0f);
    }
    __syncthreads();
    if (tid < NCLASSES) {
        float sum = bc[tid];
        #pragma unroll
        for (int cc = 0; cc < NC; cc++) sum += red[cc] * Wc[cc * NCLASSES + tid];
        out[g * NCLASSES + tid] = sum;
    }
}

// ---------------- launch ----------------

extern "C" void kernel_launch(void* const* d_in, const int* in_sizes, int n_in,
                              void* d_out, int out_size, void* d_ws, size_t ws_size,
                              hipStream_t stream) {
    const float* x    = (const float*)d_in[0];
    const float* Wl1  = (const float*)d_in[1];
    const float* bl1  = (const float*)d_in[2];
    const float* Wr1  = (const float*)d_in[3];
    const float* br1  = (const float*)d_in[4];
    const float* att1 = (const float*)d_in[5];
    const float* b1   = (const float*)d_in[6];
    const float* Wl2  = (const float*)d_in[7];
    const float* bl2  = (const float*)d_in[8];
    const float* Wr2  = (const float*)d_in[9];
    const float* br2  = (const float*)d_in[10];
    const float* att2 = (const float*)d_in[11];
    const float* b2   = (const float*)d_in[12];
    const float* Wc   = (const float*)d_in[13];
    const float* bc   = (const float*)d_in[14];
    const int* ei     = (const int*)d_in[15];
    const int* batch  = (const int*)d_in[16];
    float* out = (float*)d_out;

    const int* srcp = ei;
    const int* dstp = ei + NEDGES;

    char* ws = (char*)d_ws;
    size_t off = 0;
    auto alloc = [&](size_t bytes) -> void* {
        void* p = ws + off;
        off += (bytes + 255) & ~(size_t)255;
        return p;
    };
    _Float16* xlh  = (_Float16*)alloc(sizeof(_Float16) * (size_t)NNODES * HC);
    _Float16* xrh  = (_Float16*)alloc(sizeof(_Float16) * (size_t)NNODES * HC);
    _Float16* h1   = (_Float16*)alloc(sizeof(_Float16) * (size_t)NNODES * NC);
    float* h2      = (float*)alloc(sizeof(float) * (size_t)NNODES * NC);
    _Float16* Wlt1 = (_Float16*)alloc(sizeof(_Float16) * 512 * NFEATK);
    _Float16* Wrt1 = (_Float16*)alloc(sizeof(_Float16) * 512 * NFEATK);
    _Float16* Wlt2 = (_Float16*)alloc(sizeof(_Float16) * 512 * NC);
    _Float16* Wrt2 = (_Float16*)alloc(sizeof(_Float16) * 512 * NC);
    int*   cnt     = (int*)alloc(sizeof(int) * NNODES);
    unsigned short* csr = (unsigned short*)alloc(sizeof(unsigned short) * (size_t)NNODES * CAP);

    // prep: W transposes + bucket init (x-conversion folded into gemm1 A-staging)
    prep0_kernel<<<256, 256, 0, stream>>>(Wl1, Wr1, Wlt1, Wrt1,
                                          Wl2, Wr2, Wlt2, Wrt2, cnt, csr);
    // bucket scatter (one atomic pass)
    scatter_kernel<<<(NEDGES + 255) / 256, 256, 0, stream>>>(srcp, dstp, cnt, csr);

    const int MB = (NNODES + 63) / 64;   // 469

    // Layer 1 (A = x, f32, converted in-register during staging)
    dual_gemm_kernel<NFEATK, float><<<dim3(4, MB), 256, 0, stream>>>(x, Wlt1, Wrt1, bl1, br1, xlh, xrh);
    gat_edge_kernel<_Float16><<<NNODES / 4, 256, 0, stream>>>(xlh, xrh, att1, b1, cnt, csr, h1);

    // Layer 2 (A = h1, f16)
    dual_gemm_kernel<NC, _Float16><<<dim3(4, MB), 256, 0, stream>>>(h1, Wlt2, Wrt2, bl2, br2, xlh, xrh);
    gat_edge_kernel<float><<<NNODES / 4, 256, 0, stream>>>(xlh, xrh, att2, b2, cnt, csr, h2);

    // Pool + classify
    pool_classify_kernel<<<NG, 1024, 0, stream>>>(h2, batch, Wc, bc, out);
}

// Round 8
// 340.089 us; speedup vs baseline: 1.0505x; 1.0505x over previous
//
#include <hip/hip_runtime.h>
#include <float.h>

#define NNODES 30000
#define NEDGES 480000
#define NFEATK 128
#define NH 16
#define NC 32
#define HC 512            // NH*NC
#define NCLASSES 10
#define NG 64
#define CAP 96            // padded per-node edge capacity (max deg ~45 for Poisson(16))

using half2v = __attribute__((ext_vector_type(2))) _Float16;
using half4 = __attribute__((ext_vector_type(4))) _Float16;
using half8 = __attribute__((ext_vector_type(8))) _Float16;
using f32x4 = __attribute__((ext_vector_type(4))) float;

// ---------------- merged prep + scatter ----------------
// cnt pre-zeroed by hipMemsetAsync. Items [0,NEDGES) = real edges;
// [NEDGES, NEDGES+NNODES) = self loops. W transposes folded into the same grid.
__global__ void prep_scatter_kernel(const int* __restrict__ src, const int* __restrict__ dst,
                                    int* __restrict__ cnt, unsigned short* __restrict__ csr,
                                    const float* __restrict__ Wl1, const float* __restrict__ Wr1,
                                    _Float16* __restrict__ Wlt1, _Float16* __restrict__ Wrt1,
                                    const float* __restrict__ Wl2, const float* __restrict__ Wr2,
                                    _Float16* __restrict__ Wlt2, _Float16* __restrict__ Wrt2) {
    int gtid = blockIdx.x * blockDim.x + threadIdx.x;
    int gstride = gridDim.x * blockDim.x;
    // edge + self-loop scatter (one atomic pass)
    for (int i = gtid; i < NEDGES + NNODES; i += gstride) {
        int s, d;
        if (i < NEDGES) { s = src[i]; d = dst[i]; }
        else            { d = i - NEDGES; s = d; }
        int pos = atomicAdd(&cnt[d], 1);
        csr[d * CAP + pos] = (unsigned short)s;
    }
    // W1 transposes (both l and r)
    for (int i = gtid; i < 2 * 512 * NFEATK; i += gstride) {
        int sel = i >= 512 * NFEATK;
        int idx = i - sel * 512 * NFEATK;
        const float* W = sel ? Wr1 : Wl1;
        _Float16* Wt = sel ? Wrt1 : Wlt1;
        int n = idx & 511, k = idx >> 9;
        Wt[n * NFEATK + k] = (_Float16)W[idx];
    }
    // W2 transposes
    for (int i = gtid; i < 2 * 512 * NC; i += gstride) {
        int sel = i >= 512 * NC;
        int idx = i - sel * 512 * NC;
        const float* W = sel ? Wr2 : Wl2;
        _Float16* Wt = sel ? Wrt2 : Wlt2;
        int n = idx & 511, k = idx >> 9;
        Wt[n * NC + k] = (_Float16)W[idx];
    }
}

// ---------------- dual MFMA GEMM: merged-sel (one A-tile -> both Yl and Yr) ----------------
// K-split staging (KS=64). LDS: A 8KB + B 2x16KB = 40KB (K=128) / 20KB (K=32).
// A may be f32 (layer 1 reads x directly, converts in-register) or f16.
template <int K, typename AT>
__launch_bounds__(256)
__global__ void dual_gemm_kernel(const AT* __restrict__ A,
                                 const _Float16* __restrict__ Wlt, const _Float16* __restrict__ Wrt,
                                 const float* __restrict__ bl, const float* __restrict__ br,
                                 _Float16* __restrict__ Yl, _Float16* __restrict__ Yr) {
    constexpr int KS = (K > 64) ? 64 : K;    // staged K-chunk
    constexpr int KcS = KS / 8;              // half8 units per chunk row
    constexpr int AH = 64 * KS;
    constexpr int BH = 128 * KS;             // per sel
    constexpr int YSH = 64 * 136;
    constexpr int SMEMH = (AH + 2 * BH > YSH) ? (AH + 2 * BH) : YSH;
    __shared__ __align__(16) _Float16 smem[SMEMH];
    _Float16* as = smem;
    _Float16* bsl = smem + AH;
    _Float16* bsr = smem + AH + BH;

    int tid = threadIdx.x;
    int nbase = blockIdx.x * 128;            // 4 col-quadrants of 128
    int mb = blockIdx.y;

    int wave = tid >> 6, lane = tid & 63;
    int quad = lane >> 4, l16 = lane & 15;
    int am = l16 & (KcS - 1);

    f32x4 accl[8], accr[8];
    #pragma unroll
    for (int f = 0; f < 8; f++) {
        accl[f] = (f32x4){0.f, 0.f, 0.f, 0.f};
        accr[f] = (f32x4){0.f, 0.f, 0.f, 0.f};
    }

    #pragma unroll
    for (int ko = 0; ko < K / KS; ++ko) {
        if (ko) __syncthreads();             // protect LDS reuse across chunks
        for (int c = tid; c < 64 * KcS; c += 256) {
            int row = c / KcS, k8 = c % KcS;
            int arow = mb * 64 + row; if (arow > NNODES - 1) arow = NNODES - 1;
            half8 v;
            if constexpr (sizeof(AT) == 4) {
                const float* ap = (const float*)&A[(size_t)arow * K + (ko * KcS + k8) * 8];
                float4 f0 = *(const float4*)ap;
                float4 f1 = *(const float4*)(ap + 4);
                v = half8{(_Float16)f0.x, (_Float16)f0.y, (_Float16)f0.z, (_Float16)f0.w,
                          (_Float16)f1.x, (_Float16)f1.y, (_Float16)f1.z, (_Float16)f1.w};
            } else {
                v = *(const half8*)&A[(size_t)arow * K + (ko * KcS + k8) * 8];
            }
            *(half8*)&as[(row * KcS + (k8 ^ (row & (KcS - 1)))) * 8] = v;
        }
        for (int c = tid; c < 2 * 128 * KcS; c += 256) {
            int sel = c >= 128 * KcS;
            int cc = c - sel * 128 * KcS;
            int row = cc / KcS, k8 = cc % KcS;
            const _Float16* Bt = sel ? Wrt : Wlt;
            _Float16* bs = sel ? bsr : bsl;
            half8 v = *(const half8*)&Bt[(size_t)(nbase + row) * K + (ko * KcS + k8) * 8];
            *(half8*)&bs[(row * KcS + (k8 ^ (row & (KcS - 1)))) * 8] = v;
        }
        __syncthreads();

        #pragma unroll
        for (int kk = 0; kk < KcS; kk += 4) {
            int k8 = (kk + quad) ^ am;
            half8 a = *(const half8*)&as[((wave * 16 + l16) * KcS + k8) * 8];
            #pragma unroll
            for (int f = 0; f < 8; f++) {
                half8 b = *(const half8*)&bsl[((f * 16 + l16) * KcS + k8) * 8];
                accl[f] = __builtin_amdgcn_mfma_f32_16x16x32_f16(a, b, accl[f], 0, 0, 0);
            }
            #pragma unroll
            for (int f = 0; f < 8; f++) {
                half8 b = *(const half8*)&bsr[((f * 16 + l16) * KcS + k8) * 8];
                accr[f] = __builtin_amdgcn_mfma_f32_16x16x32_f16(a, b, accr[f], 0, 0, 0);
            }
        }
    }
    __syncthreads();

    _Float16* ys = smem;
    int mtop = mb * 64;
    // ---- Yl ----
    #pragma unroll
    for (int f = 0; f < 8; f++) {
        float bv = bl[nbase + f * 16 + l16];
        #pragma unroll
        for (int r = 0; r < 4; r++)
            ys[(wave * 16 + quad * 4 + r) * 136 + f * 16 + l16] = (_Float16)(accl[f][r] + bv);
    }
    __syncthreads();
    for (int c = tid; c < 64 * 16; c += 256) {
        int r = c >> 4, cc = (c & 15) * 8;
        int grow = mtop + r;
        if (grow < NNODES)
            *(half8*)&Yl[(size_t)grow * HC + nbase + cc] = *(half8*)&ys[r * 136 + cc];
    }
    __syncthreads();
    // ---- Yr ----
    #pragma unroll
    for (int f = 0; f < 8; f++) {
        float bv = br[nbase + f * 16 + l16];
        #pragma unroll
        for (int r = 0; r < 4; r++)
            ys[(wave * 16 + quad * 4 + r) * 136 + f * 16 + l16] = (_Float16)(accr[f][r] + bv);
    }
    __syncthreads();
    for (int c = tid; c < 64 * 16; c += 256) {
        int r = c >> 4, cc = (c & 15) * 8;
        int grow = mtop + r;
        if (grow < NNODES)
            *(half8*)&Yr[(size_t)grow * HC + nbase + cc] = *(half8*)&ys[r * 136 + cc];
    }
}

// ---------------- fused GATv2 edge stage: 4 nodes/block, 1 wave/node (proven 74us shape) ----------------
__device__ inline half2v lrelu2(half2v e) {
    // leaky(e) = max(e, 0.2*e) since slope 0.2 in (0,1)
    half2v s = e * half2v{(_Float16)0.2f, (_Float16)0.2f};
    return __builtin_elementwise_max(e, s);
}

#if __has_builtin(__builtin_amdgcn_fdot2)
#define FDOT2(a, b, c) __builtin_amdgcn_fdot2((a), (b), (c), false)
#else
__device__ inline float fdot2_sw(half2v a, half2v b, float c) {
    half2v p = a * b;
    return c + (float)p.x + (float)p.y;
}
#define FDOT2(a, b, c) fdot2_sw((a), (b), (c))
#endif

template <typename OUT>
__launch_bounds__(256)
__global__ void gat_edge_kernel(const _Float16* __restrict__ xlh, const _Float16* __restrict__ xrh,
                                const float* __restrict__ att, const float* __restrict__ bvec,
                                const int* __restrict__ cnt, const unsigned short* __restrict__ csr_src,
                                OUT* __restrict__ hout) {
    int wv = threadIdx.x >> 6;           // wave in block -> node slot
    int t = threadIdx.x & 63;            // lane in wave
    int d = blockIdx.x * 4 + wv;         // dst node (NNODES % 4 == 0)
    int col = t * 8;                     // head = t/4, 4 lanes per head

    half8 xrq = *(const half8*)&xrh[(unsigned)d * HC + col];
    half2v xr0 = {xrq[0], xrq[1]}, xr1 = {xrq[2], xrq[3]};
    half2v xr2 = {xrq[4], xrq[5]}, xr3 = {xrq[6], xrq[7]};
    float4 atta = *(const float4*)&att[col];
    float4 attb = *(const float4*)&att[col + 4];
    half2v at0 = {(_Float16)atta.x, (_Float16)atta.y};
    half2v at1 = {(_Float16)atta.z, (_Float16)atta.w};
    half2v at2 = {(_Float16)attb.x, (_Float16)attb.y};
    half2v at3 = {(_Float16)attb.z, (_Float16)attb.w};

    int beg = d * CAP, end = beg + cnt[d];

    float l = 0.f;
    float a[8];
    #pragma unroll
    for (int c = 0; c < 8; c++) a[c] = 0.f;

    for (int i = beg; i < end; i += 4) {
        int n = end - i;
        int s0 = csr_src[i];
        int s1 = csr_src[n > 1 ? i + 1 : i];
        int s2 = csr_src[n > 2 ? i + 2 : i];
        int s3 = csr_src[n > 3 ? i + 3 : i];
        half8 q0 = *(const half8*)&xlh[(unsigned)s0 * HC + col];
        half8 q1 = *(const half8*)&xlh[(unsigned)s1 * HC + col];
        half8 q2 = *(const half8*)&xlh[(unsigned)s2 * HC + col];
        half8 q3 = *(const half8*)&xlh[(unsigned)s3 * HC + col];

        // packed-f16 score: e = leaky(xl+xr); v += dot2(e, att)  (f32 accumulate)
        float v0 = 0.f, v1 = 0.f, v2 = 0.f, v3 = 0.f;
        v0 = FDOT2(lrelu2(half2v{q0[0], q0[1]} + xr0), at0, v0);
        v0 = FDOT2(lrelu2(half2v{q0[2], q0[3]} + xr1), at1, v0);
        v0 = FDOT2(lrelu2(half2v{q0[4], q0[5]} + xr2), at2, v0);
        v0 = FDOT2(lrelu2(half2v{q0[6], q0[7]} + xr3), at3, v0);
        v1 = FDOT2(lrelu2(half2v{q1[0], q1[1]} + xr0), at0, v1);
        v1 = FDOT2(lrelu2(half2v{q1[2], q1[3]} + xr1), at1, v1);
        v1 = FDOT2(lrelu2(half2v{q1[4], q1[5]} + xr2), at2, v1);
        v1 = FDOT2(lrelu2(half2v{q1[6], q1[7]} + xr3), at3, v1);
        v2 = FDOT2(lrelu2(half2v{q2[0], q2[1]} + xr0), at0, v2);
        v2 = FDOT2(lrelu2(half2v{q2[2], q2[3]} + xr1), at1, v2);
        v2 = FDOT2(lrelu2(half2v{q2[4], q2[5]} + xr2), at2, v2);
        v2 = FDOT2(lrelu2(half2v{q2[6], q2[7]} + xr3), at3, v2);
        v3 = FDOT2(lrelu2(half2v{q3[0], q3[1]} + xr0), at0, v3);
        v3 = FDOT2(lrelu2(half2v{q3[2], q3[3]} + xr1), at1, v3);
        v3 = FDOT2(lrelu2(half2v{q3[4], q3[5]} + xr2), at2, v3);
        v3 = FDOT2(lrelu2(half2v{q3[6], q3[7]} + xr3), at3, v3);

        // head reduce: 4 lanes per head -> 2 butterfly levels
        v0 += __shfl_xor(v0, 1); v1 += __shfl_xor(v1, 1);
        v2 += __shfl_xor(v2, 1); v3 += __shfl_xor(v3, 1);
        v0 += __shfl_xor(v0, 2); v1 += __shfl_xor(v1, 2);
        v2 += __shfl_xor(v2, 2); v3 += __shfl_xor(v3, 2);

        float p0 = __expf(v0);
        float p1 = (n > 1) ? __expf(v1) : 0.f;
        float p2 = (n > 2) ? __expf(v2) : 0.f;
        float p3 = (n > 3) ? __expf(v3) : 0.f;
        l += (p0 + p1) + (p2 + p3);

        // aggregation: f32 accumulate, f16 operand -> v_fma_mix
        #pragma unroll
        for (int c = 0; c < 8; c++) {
            a[c] += p0 * (float)q0[c];
            a[c] += p1 * (float)q1[c];
            a[c] += p2 * (float)q2[c];
            a[c] += p3 * (float)q3[c];
        }
    }

    // normalize per (node, head) BEFORE head-mean: l is uniform within a
    // 4-lane head group, distinct across heads.
    float inv = 1.0f / l;
    #pragma unroll
    for (int c = 0; c < 8; c++) a[c] *= inv;

    // head-mean in-register: sum over the 16 lanes with equal (t & 3)
    #pragma unroll
    for (int off = 4; off < 64; off <<= 1) {
        #pragma unroll
        for (int c = 0; c < 8; c++) a[c] += __shfl_xor(a[c], off);
    }

    if (t < 4) {
        #pragma unroll
        for (int c = 0; c < 8; c++) {
            float r = a[c] * (1.0f / (float)NH) + bvec[t * 8 + c];
            r = (r > 0.f) ? r : 0.01f * r;
            hout[(size_t)d * NC + t * 8 + c] = (OUT)r;
        }
    }
}

// ---------------- fused pool + classifier (unchanged) ----------------
__launch_bounds__(1024)
__global__ void pool_classify_kernel(const float* __restrict__ h, const int* __restrict__ batch,
                                     const float* __restrict__ Wc, const float* __restrict__ bc,
                                     float* __restrict__ out) {
    int g = blockIdx.x;
    int lo = 0, hi = NNODES;
    while (lo < hi) { int mid = (lo + hi) >> 1; if (batch[mid] < g) lo = mid + 1; else hi = mid; }
    int start = lo;
    hi = NNODES;
    while (lo < hi) { int mid = (lo + hi) >> 1; if (batch[mid] <= g) lo = mid + 1; else hi = mid; }
    int endn = lo;
    int cntg = endn - start;

    int tid = threadIdx.x;
    int c = tid & 31, nl = tid >> 5;              // 32 node-lanes x 32 channels
    float s = 0.f;
    for (int n = start + nl; n < endn; n += 32) s += h[n * NC + c];
    __shared__ float red[1024];
    red[tid] = s;
    __syncthreads();
    if (tid < 32) {
        float t = 0.f;
        #pragma unroll
        for (int j = 0; j < 32; j++) t += red[j * 32 + tid];
        red[tid] = t / fmaxf((float)cntg, 1.0f);
    }
    __syncthreads();
    if (tid < NCLASSES) {
        float sum = bc[tid];
        #pragma unroll
        for (int cc = 0; cc < NC; cc++) sum += red[cc] * Wc[cc * NCLASSES + tid];
        out[g * NCLASSES + tid] = sum;
    }
}

// ---------------- launch ----------------

extern "C" void kernel_launch(void* const* d_in, const int* in_sizes, int n_in,
                              void* d_out, int out_size, void* d_ws, size_t ws_size,
                              hipStream_t stream) {
    const float* x    = (const float*)d_in[0];
    const float* Wl1  = (const float*)d_in[1];
    const float* bl1  = (const float*)d_in[2];
    const float* Wr1  = (const float*)d_in[3];
    const float* br1  = (const float*)d_in[4];
    const float* att1 = (const float*)d_in[5];
    const float* b1   = (const float*)d_in[6];
    const float* Wl2  = (const float*)d_in[7];
    const float* bl2  = (const float*)d_in[8];
    const float* Wr2  = (const float*)d_in[9];
    const float* br2  = (const float*)d_in[10];
    const float* att2 = (const float*)d_in[11];
    const float* b2   = (const float*)d_in[12];
    const float* Wc   = (const float*)d_in[13];
    const float* bc   = (const float*)d_in[14];
    const int* ei     = (const int*)d_in[15];
    const int* batch  = (const int*)d_in[16];
    float* out = (float*)d_out;

    const int* srcp = ei;
    const int* dstp = ei + NEDGES;

    char* ws = (char*)d_ws;
    size_t off = 0;
    auto alloc = [&](size_t bytes) -> void* {
        void* p = ws + off;
        off += (bytes + 255) & ~(size_t)255;
        return p;
    };
    _Float16* xlh  = (_Float16*)alloc(sizeof(_Float16) * (size_t)NNODES * HC);
    _Float16* xrh  = (_Float16*)alloc(sizeof(_Float16) * (size_t)NNODES * HC);
    _Float16* h1   = (_Float16*)alloc(sizeof(_Float16) * (size_t)NNODES * NC);
    float* h2      = (float*)alloc(sizeof(float) * (size_t)NNODES * NC);
    _Float16* Wlt1 = (_Float16*)alloc(sizeof(_Float16) * 512 * NFEATK);
    _Float16* Wrt1 = (_Float16*)alloc(sizeof(_Float16) * 512 * NFEATK);
    _Float16* Wlt2 = (_Float16*)alloc(sizeof(_Float16) * 512 * NC);
    _Float16* Wrt2 = (_Float16*)alloc(sizeof(_Float16) * 512 * NC);
    int*   cnt     = (int*)alloc(sizeof(int) * NNODES);
    unsigned short* csr = (unsigned short*)alloc(sizeof(unsigned short) * (size_t)NNODES * CAP);

    // zero degree counters (async DMA, graph-capture-safe)
    hipMemsetAsync(cnt, 0, sizeof(int) * NNODES, stream);

    // merged prep + scatter: W transposes + edge/self-loop bucket scatter
    prep_scatter_kernel<<<(NEDGES + NNODES + 255) / 256, 256, 0, stream>>>(
        srcp, dstp, cnt, csr, Wl1, Wr1, Wlt1, Wrt1, Wl2, Wr2, Wlt2, Wrt2);

    const int MB = (NNODES + 63) / 64;   // 469

    // Layer 1 (A = x, f32, converted in-register during staging)
    dual_gemm_kernel<NFEATK, float><<<dim3(4, MB), 256, 0, stream>>>(x, Wlt1, Wrt1, bl1, br1, xlh, xrh);
    gat_edge_kernel<_Float16><<<NNODES / 4, 256, 0, stream>>>(xlh, xrh, att1, b1, cnt, csr, h1);

    // Layer 2 (A = h1, f16)
    dual_gemm_kernel<NC, _Float16><<<dim3(4, MB), 256, 0, stream>>>(h1, Wlt2, Wrt2, bl2, br2, xlh, xrh);
    gat_edge_kernel<float><<<NNODES / 4, 256, 0, stream>>>(xlh, xrh, att2, b2, cnt, csr, h2);

    // Pool + classify
    pool_classify_kernel<<<NG, 1024, 0, stream>>>(h2, batch, Wc, bc, out);
}